// Round 11
// baseline (26.164 us; speedup 1.0000x reference)
//
#include <hip/hip_runtime.h>
#include <math.h>

// FeedForwardQuantum, analytically collapsed circuit:
//   z_j = cos(theta_j) * cos(x.W1_j + b1_j)
//   ex[w] = prod_{j<=w} z_j (w>=1); ex[0] = prod_{j=1..7} z_j
//   out = relu(ex @ W2^T + b2)
//
// Producer/consumer wave specialization: waves 0-1 produce z (HBM reads),
// waves 2-3 consume z -> out (HBM writes), pipelined through double-buffered
// LDS with one uniform barrier per phase. In steady state each phase mixes
// reads (round r) with writes (round r-1) -> continuous HBM stream instead
// of read-burst / idle / write-burst lockstep. Pipeline state lives in LDS,
// not registers, so the R6/R9 spill pathology cannot occur.

constexpr int EMBED  = 768;
constexpr int NQ     = 8;
constexpr int BLOCK  = 256;             // 4 waves: 2 producer + 2 consumer
constexpr int ROUNDS = 4;
constexpr int TPR    = 4;               // tokens per round
constexpr int TPB    = ROUNDS * TPR;    // 16 tokens per block

// NOTE: macro params must not be named x/y/z/w (member-accessor collision)
#define DOT4(va, vb, sv) sv = fmaf((va).x, (vb).x, fmaf((va).y, (vb).y, \
                         fmaf((va).z, (vb).z, fmaf((va).w, (vb).w, (sv)))))

// packed butterfly: 10 shuffles -> every lane holds full sum for q = lane&7
#define PACKED_REDUCE(acc, S) {                                          \
    float k0 = c0 ? acc[1] : acc[0], g0 = c0 ? acc[0] : acc[1];          \
    float k1 = c0 ? acc[3] : acc[2], g1 = c0 ? acc[2] : acc[3];          \
    float k2 = c0 ? acc[5] : acc[4], g2 = c0 ? acc[4] : acc[5];          \
    float k3 = c0 ? acc[7] : acc[6], g3 = c0 ? acc[6] : acc[7];          \
    float v0 = k0 + __shfl_xor(g0, 1, 64);                               \
    float v1 = k1 + __shfl_xor(g1, 1, 64);                               \
    float v2 = k2 + __shfl_xor(g2, 1, 64);                               \
    float v3 = k3 + __shfl_xor(g3, 1, 64);                               \
    float ka = c1 ? v1 : v0, ga = c1 ? v0 : v1;                          \
    float kb = c1 ? v3 : v2, gb = c1 ? v2 : v3;                          \
    float u0 = ka + __shfl_xor(ga, 2, 64);                               \
    float u1 = kb + __shfl_xor(gb, 2, 64);                               \
    float kc = c2 ? u1 : u0, gc = c2 ? u0 : u1;                          \
    float s  = kc + __shfl_xor(gc, 4, 64);                               \
    s += __shfl_xor(s, 8, 64);                                           \
    s += __shfl_xor(s, 16, 64);                                          \
    s += __shfl_xor(s, 32, 64);                                          \
    S = s; }

__global__ __launch_bounds__(BLOCK, 4) void ffq_kernel(
    const float* __restrict__ x,  const float* __restrict__ W1,
    const float* __restrict__ b1, const float* __restrict__ theta,
    const float* __restrict__ W2, const float* __restrict__ b2,
    float* __restrict__ out, int ntok)
{
    __shared__ float w2t[NQ][EMBED];                    // transposed W2 (24 KB)
    __shared__ __align__(16) float zbuf[2][TPR][NQ];    // double-buffered z pipe

    const int tid  = threadIdx.x;
    const int wave = tid >> 6;
    const int lane = tid & 63;
    const int gbase = blockIdx.x * TPB;

    // ---- stage W2 transposed (all waves): coalesced reads, scatter writes ----
    {
        const float4* W24 = (const float4*)W2;
        for (int i = tid; i < EMBED * NQ / 4; i += BLOCK) {
            const float4 v = W24[i];
            const int f = 4 * i;                 // flat = e*8 + q
            w2t[(f + 0) & 7][(f + 0) >> 3] = v.x;
            w2t[(f + 1) & 7][(f + 1) >> 3] = v.y;
            w2t[(f + 2) & 7][(f + 2) >> 3] = v.z;
            w2t[(f + 3) & 7][(f + 3) >> 3] = v.w;
        }
    }

    const int q_own = lane & 7;
    const int osel  = (lane >> 3) & 1;
    const bool c0 = lane & 1, c1 = lane & 2, c2 = lane & 4;
    const float4* x4  = (const float4*)x;
    const float4* W14 = (const float4*)W1;

    // producer-only constants
    float costh = 0.f, b1q = 0.f;
    if (wave < 2) { costh = __cosf(theta[q_own]); b1q = b1[q_own]; }

    // consumer-only constants (b2 hoisted)
    float4 bb0, bb1, bb2;
    if (wave >= 2) {
        const float4* b24 = (const float4*)b2;
        bb0 = b24[lane]; bb1 = b24[lane + 64]; bb2 = b24[lane + 128];
    }

    __syncthreads();   // w2t ready

    #pragma unroll 1
    for (int ph = 0; ph <= ROUNDS; ++ph) {
        if (wave < 2) {
            // ---------------- PRODUCER: round ph (ph < ROUNDS) ----------------
            if (ph < ROUNDS) {
                const int ta = min(gbase + ph * TPR + 2 * wave,     ntok - 1);
                const int tb = min(gbase + ph * TPR + 2 * wave + 1, ntok - 1);
                const float4 xa0 = x4[(size_t)ta * (EMBED / 4) + lane];
                const float4 xa1 = x4[(size_t)ta * (EMBED / 4) + lane + 64];
                const float4 xa2 = x4[(size_t)ta * (EMBED / 4) + lane + 128];
                const float4 xb0 = x4[(size_t)tb * (EMBED / 4) + lane];
                const float4 xb1 = x4[(size_t)tb * (EMBED / 4) + lane + 64];
                const float4 xb2 = x4[(size_t)tb * (EMBED / 4) + lane + 128];

                float acc0[NQ], acc1[NQ];
                #pragma unroll
                for (int q = 0; q < NQ; ++q) {
                    const float4 w0  = W14[q * (EMBED / 4) + lane];
                    const float4 w1  = W14[q * (EMBED / 4) + lane + 64];
                    const float4 w2v = W14[q * (EMBED / 4) + lane + 128];
                    float s0 = 0.f, s1 = 0.f;
                    DOT4(xa0, w0, s0); DOT4(xa1, w1, s0); DOT4(xa2, w2v, s0);
                    DOT4(xb0, w0, s1); DOT4(xb1, w1, s1); DOT4(xb2, w2v, s1);
                    acc0[q] = s0; acc1[q] = s1;
                }

                float S0, S1;
                PACKED_REDUCE(acc0, S0);
                PACKED_REDUCE(acc1, S1);

                const float zval = costh * __cosf((osel ? S1 : S0) + b1q);
                if (lane < 16) zbuf[ph & 1][2 * wave + osel][q_own] = zval;
            }
        } else {
            // ---------------- CONSUMER: round ph-1 (ph > 0) ----------------
            if (ph > 0) {
                const int r  = ph - 1;
                const int cw = wave - 2;
                const int ta = min(gbase + r * TPR + 2 * cw,     ntok - 1);
                const int tb = min(gbase + r * TPR + 2 * cw + 1, ntok - 1);

                const float4 za0 = ((const float4*)zbuf[r & 1][2 * cw    ])[0];
                const float4 za1 = ((const float4*)zbuf[r & 1][2 * cw    ])[1];
                const float4 zc0 = ((const float4*)zbuf[r & 1][2 * cw + 1])[0];
                const float4 zc1 = ((const float4*)zbuf[r & 1][2 * cw + 1])[1];

                float ex0[NQ], ex1[NQ];
                {
                    const float zq[NQ] = { za0.x, za0.y, za0.z, za0.w,
                                           za1.x, za1.y, za1.z, za1.w };
                    float p = zq[0];
                    #pragma unroll
                    for (int q = 1; q < NQ; ++q) { p *= zq[q]; ex0[q] = p; }
                    float sfx = zq[1];
                    #pragma unroll
                    for (int q = 2; q < NQ; ++q) sfx *= zq[q];
                    ex0[0] = sfx;
                }
                {
                    const float zq[NQ] = { zc0.x, zc0.y, zc0.z, zc0.w,
                                           zc1.x, zc1.y, zc1.z, zc1.w };
                    float p = zq[0];
                    #pragma unroll
                    for (int q = 1; q < NQ; ++q) { p *= zq[q]; ex1[q] = p; }
                    float sfx = zq[1];
                    #pragma unroll
                    for (int q = 2; q < NQ; ++q) sfx *= zq[q];
                    ex1[0] = sfx;
                }

                #pragma unroll
                for (int k = 0; k < 3; ++k) {
                    const int idx = lane + 64 * k;
                    float4 r0 = (k == 0) ? bb0 : (k == 1) ? bb1 : bb2;
                    float4 r1 = r0;
                    #pragma unroll
                    for (int q = 0; q < NQ; ++q) {
                        const float4 wv = ((const float4*)&w2t[q][0])[idx];
                        r0.x = fmaf(ex0[q], wv.x, r0.x);
                        r0.y = fmaf(ex0[q], wv.y, r0.y);
                        r0.z = fmaf(ex0[q], wv.z, r0.z);
                        r0.w = fmaf(ex0[q], wv.w, r0.w);
                        r1.x = fmaf(ex1[q], wv.x, r1.x);
                        r1.y = fmaf(ex1[q], wv.y, r1.y);
                        r1.z = fmaf(ex1[q], wv.z, r1.z);
                        r1.w = fmaf(ex1[q], wv.w, r1.w);
                    }
                    const float4 o0 = make_float4(fmaxf(r0.x, 0.f), fmaxf(r0.y, 0.f),
                                                  fmaxf(r0.z, 0.f), fmaxf(r0.w, 0.f));
                    const float4 o1 = make_float4(fmaxf(r1.x, 0.f), fmaxf(r1.y, 0.f),
                                                  fmaxf(r1.z, 0.f), fmaxf(r1.w, 0.f));
                    ((float4*)(out + (size_t)ta * EMBED))[idx] = o0;
                    ((float4*)(out + (size_t)tb * EMBED))[idx] = o1;
                }
            }
        }
        if (ph < ROUNDS) __syncthreads();   // block-uniform barrier
    }
}

extern "C" void kernel_launch(void* const* d_in, const int* in_sizes, int n_in,
                              void* d_out, int out_size, void* d_ws, size_t ws_size,
                              hipStream_t stream) {
    const float* x     = (const float*)d_in[0];
    const float* W1    = (const float*)d_in[1];
    const float* b1    = (const float*)d_in[2];
    const float* theta = (const float*)d_in[3];
    const float* W2    = (const float*)d_in[4];
    const float* b2    = (const float*)d_in[5];
    float* out = (float*)d_out;

    const int ntok = in_sizes[0] / EMBED;          // 16384
    const int grid = (ntok + TPB - 1) / TPB;       // 1024 = 4 blocks/CU
    hipLaunchKernelGGL(ffq_kernel, dim3(grid), dim3(BLOCK), 0, stream,
                       x, W1, b1, theta, W2, b2, out, ntok);
}